// Round 5
// baseline (449.946 us; speedup 1.0000x reference)
//
#include <hip/hip_runtime.h>
#include <hip/hip_bf16.h>
#include <math.h>

// GATNet: hh = h@W_emb+b_emb -> GAT(8 heads,32,residual) -> GAT(1 head,32) -> out f32.
// Edge-feature branch of the reference is dead code (del e_feat) -> skipped.
// R16: megakernel retry WITHOUT cooperative launch (R15 hung the container; suspected
// coop-launch/graph-capture incompat or grid.sync co-residency deadlock). Same 10
// phases in one regular kernel; grid-wide sync is a hand-rolled device-scope-atomic
// barrier (threadfence + arrival count + generation flag, s_sleep backoff, bounded
// spin so a bug can't hang the container). Barrier state is memset-zeroed each run
// (ws is re-poisoned between iterations). Grid occupancy-clamped to <=4 blocks/CU
// (1024 blocks) so all blocks are co-resident. Phase math bit-identical to R14.

#define HDIM 256
#define ODIM 32

typedef unsigned short u16;
typedef __attribute__((ext_vector_type(8))) short short8;
typedef __attribute__((ext_vector_type(4))) float f32x4;

__device__ __forceinline__ float bf2f(u16 u) { return __uint_as_float(((unsigned)u) << 16); }
__device__ __forceinline__ u16 f2bf(float f) {
    unsigned x = __float_as_uint(f);
    return (u16)((x + 0x7FFFu + ((x >> 16) & 1u)) >> 16);  // RNE
}
// exp(leaky_relu(l)); logits O(0.1), max-subtraction unnecessary (identical ratios)
__device__ __forceinline__ float edgew(float l) {
    l = (l > 0.f) ? l : 0.2f * l;
    l = fminf(fmaxf(l, -30.f), 30.f);
    return __expf(l);
}

// grid barrier #it (0-based). cnt/gen zeroed before launch. Device-scope atomics are
// coherent across XCDs; __threadfence = agent-scope release/acquire. Bounded spin:
// on pathological failure we break (wrong answer, clean termination) instead of
// hanging the container.
__device__ __forceinline__ void gbar(int* cnt, int* gen, int nb, int it) {
    __syncthreads();
    if (threadIdx.x == 0) {
        __threadfence();
        int prev = atomicAdd(cnt, 1);
        if (prev == nb * (it + 1) - 1) {
            atomicExch(gen, it + 1);
        } else {
            long guard = 0;
            while (atomicAdd(gen, 0) < it + 1) {
                __builtin_amdgcn_s_sleep(2);
                if (++guard > (1L << 24)) break;  // safety valve ~1e7 probes
            }
        }
        __threadfence();
    }
    __syncthreads();
}

struct MegaP {
    const float *in_h, *W_emb, *fc1w, *fc2w;
    const int *src, *dst;
    const float *bemb, *al1, *ar1, *g1, *b1, *al2, *ar2, *g2, *b2;
    int* deg;
    float* stats;   // 512 floats; stats2 = stats+512 (64 floats); then barrier state
    float* stats2;
    int *cnt, *gen;
    int *offs, *cursor, *srcs;
    u16 *Ah, *Bemb, *Bfc1, *Bfc2;
    u16 *hh, *feat1, *el1, *er1, *rst;
    float *feat2, *el2, *er2, *rst2, *out;
    int N, E, n4, NB16, NBF;
};

__global__ __launch_bounds__(256, 4) void mega(MegaP p) {
    __shared__ alignas(16) unsigned char smem[8192];
    const int t = threadIdx.x;
    const int bid = (int)blockIdx.x;
    const int GRID = (int)gridDim.x;
    const int gtid = bid * 256 + t;
    const int GT = GRID * 256;
    int bi = 0;  // barrier index

    // ================= P0: cvt h -> bf16 (deg/stats/barrier pre-zeroed by memset) ==
    for (int i = gtid; i < p.n4; i += GT) {
        float4 v = ((const float4*)p.in_h)[i];
        ushort4 o = {f2bf(v.x), f2bf(v.y), f2bf(v.z), f2bf(v.w)};
        ((ushort4*)p.Ah)[i] = o;
    }
    gbar(p.cnt, p.gen, GRID, bi++);

    // ================= P1: degree count =================
    for (int i = gtid; i < p.E; i += GT) {
        unsigned d = (unsigned)p.dst[i];
        if (d < (unsigned)p.N) atomicAdd(&p.deg[d], 1);
    }
    gbar(p.cnt, p.gen, GRID, bi++);

    // ================= P2: block0 CSR scan || others B-swizzles =================
    if (bid == 0) {
        int* wsum = (int*)smem;
        const int n = p.N;
        int chunk = (n + 255) / 256;
        int lo = t * chunk, hi = lo + chunk;
        if (hi > n) hi = n;
        if (lo > n) lo = n;
        int s = 0;
        for (int i = lo; i < hi; i++) s += p.deg[i];
        int v = s;
#pragma unroll
        for (int d = 1; d < 64; d <<= 1) {
            int nb = __shfl_up(v, d, 64);
            if ((t & 63) >= d) v += nb;
        }
        if ((t & 63) == 63) wsum[t >> 6] = v;
        __syncthreads();
        int woff = 0;
#pragma unroll
        for (int w = 0; w < 4; w++)
            if (w < (t >> 6)) woff += wsum[w];
        int run = woff + v - s;
        for (int i = lo; i < hi; i++) {
            p.offs[i] = run;
            p.cursor[i] = run;
            run += p.deg[i];
        }
        if (t == 255) p.offs[n] = run;
    } else {
        // 52 swizzle units: job1(Bemb)=16, job2(Bfc1)=32, job3(Bfc2)=4
        for (int u = bid - 1; u < 52; u += GRID - 1) {
            const float* B; u16* O; int K, NC, ub;
            if (u < 16) { B = p.W_emb; O = p.Bemb; K = 128; NC = 256; ub = u; }
            else if (u < 48) { B = p.fc1w; O = p.Bfc1; K = 256; NC = 256; ub = u - 16; }
            else { B = p.fc2w; O = p.Bfc2; K = 256; NC = 32; ub = u - 48; }
            int idx = ub * 256 + t;
            int KB = K / 32;
            int TOT = (NC / 16) * KB * 64;
            if (idx < TOT) {
                int lane = idx & 63;
                int kb = (idx >> 6) % KB;
                int ct = (idx >> 6) / KB;
                int nn = ct * 16 + (lane & 15);
                int k0 = kb * 32 + (lane >> 4) * 8;
                u16* dstp = O + (size_t)idx * 8;
#pragma unroll
                for (int j = 0; j < 8; j++) dstp[j] = f2bf(B[(size_t)(k0 + j) * NC + nn]);
            }
        }
    }
    gbar(p.cnt, p.gen, GRID, bi++);

    // ================= P3: emb->fc1 GEMM tiles + CSR fill =================
    for (int u = bid; u < p.NB16 + p.NBF; u += GRID) {
        if (u >= p.NB16) {  // CSR fill unit (block-uniform branch)
            int i = (u - p.NB16) * 256 + t;
            if (i < p.E) {
                unsigned d = (unsigned)p.dst[i];
                if (d < (unsigned)p.N) {
                    int pp = atomicAdd(&p.cursor[d], 1);
                    if ((unsigned)pp < (unsigned)p.E) p.srcs[pp] = p.src[i];
                }
            }
            continue;
        }
        u16* tile = (u16*)smem;  // 8 KB: swizzled hh tile, then plain feat1 tile
        const int lane = t & 63, w = t >> 6;
        const int rb = u * 16;
        const int m = lane & 15, q = lane >> 4;
        const int arow = rb + m;
        const int M = p.N;
        // stage 1: emb GEMM (K=128), wave w owns ct = w*4..w*4+3
        short8 a0[4];
#pragma unroll
        for (int kb = 0; kb < 4; kb++) {
            if (arow < M) a0[kb] = *(const short8*)(p.Ah + (size_t)arow * 128 + kb * 32 + q * 8);
            else a0[kb] = (short8){0, 0, 0, 0, 0, 0, 0, 0};
        }
        const short8* B8 = (const short8*)p.Bemb;
#pragma unroll
        for (int ct2 = 0; ct2 < 4; ct2++) {
            const int ct = w * 4 + ct2;
            f32x4 acc = {0.f, 0.f, 0.f, 0.f};
#pragma unroll
            for (int kb = 0; kb < 4; kb++)
                acc = __builtin_amdgcn_mfma_f32_16x16x32_bf16(a0[kb], B8[(ct * 4 + kb) * 64 + lane], acc, 0, 0, 0);
            float bv = p.bemb[ct * 16 + m];
#pragma unroll
            for (int r = 0; r < 4; r++) {
                int rl = q * 4 + r;
                int ro = rb + rl;
                u16 hv = 0;
                if (ro < M) {
                    hv = f2bf(acc[r] + bv);
                    p.hh[(size_t)ro * 256 + ct * 16 + m] = hv;
                }
                int byte = rl * 512 + (ct * 16 + m) * 2;
                tile[(byte ^ ((rl & 7) << 4)) >> 1] = hv;  // XOR-swizzle
            }
        }
        __syncthreads();
        // stage 2: fc1 A-fragments from LDS
        short8 af[8];
        {
            int rl = m;
#pragma unroll
            for (int kb = 0; kb < 8; kb++) {
                int byte = rl * 512 + kb * 64 + q * 16;
                af[kb] = *(const short8*)(tile + ((byte ^ ((rl & 7) << 4)) >> 1));
            }
        }
        __syncthreads();
        const short8* Bf = (const short8*)p.Bfc1;
#pragma unroll
        for (int ct2 = 0; ct2 < 4; ct2++) {
            const int ct = w * 4 + ct2;
            f32x4 acc = {0.f, 0.f, 0.f, 0.f};
#pragma unroll
            for (int kb = 0; kb < 8; kb++)
                acc = __builtin_amdgcn_mfma_f32_16x16x32_bf16(af[kb], Bf[(ct * 8 + kb) * 64 + lane], acc, 0, 0, 0);
#pragma unroll
            for (int r = 0; r < 4; r++) {
                int rl = q * 4 + r;
                int ro = rb + rl;
                u16 v = 0;
                if (ro < M) {
                    v = f2bf(acc[r]);
                    p.feat1[(size_t)ro * 256 + ct * 16 + m] = v;
                }
                tile[rl * 256 + ct * 16 + m] = v;  // plain layout for elr epilogue
            }
        }
        __syncthreads();
        // stage 3: el/er epilogue (16 nodes x 8 heads)
        if (t < 128) {
            int nl = t >> 3, h2 = t & 7;
            int node = rb + nl;
            if (node < M) {
                float a_ = 0.f, b_ = 0.f;
#pragma unroll
                for (int d = 0; d < 32; d++) {
                    float fv = bf2f(tile[nl * 256 + h2 * 32 + d]);
                    a_ += fv * p.al1[h2 * 32 + d];
                    b_ += fv * p.ar1[h2 * 32 + d];
                }
                p.el1[node * 8 + h2] = f2bf(a_);
                p.er1[node * 8 + h2] = f2bf(b_);
            }
        }
        __syncthreads();  // tile reuse safety if block loops
    }
    gbar(p.cnt, p.gen, GRID, bi++);

    // ================= P4: agg1 =================
    {
        const int NU = (p.N + 3) >> 2;
        for (int u = bid; u < NU; u += GRID) {
            const int node = u * 4 + (t >> 6);
            const int lane = t & 63;
            if (node < p.N) {
                const int h = lane >> 3;
                int beg = p.offs[node], end = p.offs[node + 1];
                if (beg < 0) beg = 0;
                if (end > p.E) end = p.E;
                float ern = bf2f(p.er1[node * 8 + h]);
                float ax = 0.f, ay = 0.f, az = 0.f, aw = 0.f, sw = 0.f;
                int j = beg;
                int end4 = beg + ((end - beg) & ~3);
                for (; j < end4; j += 4) {
                    int s0 = p.srcs[j], s1 = p.srcs[j + 1], s2 = p.srcs[j + 2], s3 = p.srcs[j + 3];
                    unsigned c0 = (unsigned)s0 < (unsigned)p.N, c1 = (unsigned)s1 < (unsigned)p.N;
                    unsigned c2 = (unsigned)s2 < (unsigned)p.N, c3 = (unsigned)s3 < (unsigned)p.N;
                    s0 = c0 ? s0 : 0; s1 = c1 ? s1 : 0; s2 = c2 ? s2 : 0; s3 = c3 ? s3 : 0;
                    u16 e0 = p.el1[s0 * 8 + h], e1 = p.el1[s1 * 8 + h];
                    u16 e2 = p.el1[s2 * 8 + h], e3 = p.el1[s3 * 8 + h];
                    ushort4 f0 = *(const ushort4*)(p.feat1 + (size_t)s0 * 256 + lane * 4);
                    ushort4 f1 = *(const ushort4*)(p.feat1 + (size_t)s1 * 256 + lane * 4);
                    ushort4 f2 = *(const ushort4*)(p.feat1 + (size_t)s2 * 256 + lane * 4);
                    ushort4 f3 = *(const ushort4*)(p.feat1 + (size_t)s3 * 256 + lane * 4);
                    float w0 = c0 ? edgew(bf2f(e0) + ern) : 0.f;
                    float w1 = c1 ? edgew(bf2f(e1) + ern) : 0.f;
                    float w2 = c2 ? edgew(bf2f(e2) + ern) : 0.f;
                    float w3 = c3 ? edgew(bf2f(e3) + ern) : 0.f;
                    sw += w0 + w1 + w2 + w3;
                    ax += w0 * bf2f(f0.x) + w1 * bf2f(f1.x) + w2 * bf2f(f2.x) + w3 * bf2f(f3.x);
                    ay += w0 * bf2f(f0.y) + w1 * bf2f(f1.y) + w2 * bf2f(f2.y) + w3 * bf2f(f3.y);
                    az += w0 * bf2f(f0.z) + w1 * bf2f(f1.z) + w2 * bf2f(f2.z) + w3 * bf2f(f3.z);
                    aw += w0 * bf2f(f0.w) + w1 * bf2f(f1.w) + w2 * bf2f(f2.w) + w3 * bf2f(f3.w);
                }
                for (; j < end; j++) {
                    int s = p.srcs[j];
                    if ((unsigned)s >= (unsigned)p.N) continue;
                    float wv = edgew(bf2f(p.el1[s * 8 + h]) + ern);
                    ushort4 f4 = *(const ushort4*)(p.feat1 + (size_t)s * 256 + lane * 4);
                    sw += wv;
                    ax += wv * bf2f(f4.x);
                    ay += wv * bf2f(f4.y);
                    az += wv * bf2f(f4.z);
                    aw += wv * bf2f(f4.w);
                }
                float inv = 1.f / (sw + 1e-16f);
                ushort4 o;
                o.x = f2bf(ax * inv); o.y = f2bf(ay * inv);
                o.z = f2bf(az * inv); o.w = f2bf(aw * inv);
                *(ushort4*)(p.rst + (size_t)node * 256 + lane * 4) = o;
            }
        }
    }
    gbar(p.cnt, p.gen, GRID, bi++);

    // ================= P5: bn stats over rst (256 cols) =================
    {
        const int NU = (p.N + 39) / 40;
        for (int u = bid; u < NU; u += GRID) {
            int rbeg = u * 40;
            int rend = rbeg + 40;
            if (rend > p.N) rend = p.N;
            float s = 0.f, s2 = 0.f;
            for (int r = rbeg; r < rend; r++) {
                float x = bf2f(p.rst[(size_t)r * 256 + t]);
                s += x;
                s2 += x * x;
            }
            atomicAdd(&p.stats[t], s);
            atomicAdd(&p.stats[256 + t], s2);
        }
    }
    gbar(p.cnt, p.gen, GRID, bi++);

    // ================= P6: fc2 GEMM (bn_apply1+residual fused) + elr2 =================
    {
        const float invN = 1.f / p.N;
        float* sc = (float*)smem;        // 256
        float* sh = sc + 256;            // 256
        float* red = sh + 256;           // 512
        float* tl = red + 512;           // 512
        const int M = p.N;
        for (int u = bid; u < p.NB16; u += GRID) {
            {
                float mu = p.stats[t] * invN;
                float var = fmaxf(p.stats[256 + t] * invN - mu * mu, 0.f);
                float s = p.g1[t] * rsqrtf(var + 1e-5f);
                sc[t] = s;
                sh[t] = p.b1[t] - mu * s;
            }
            __syncthreads();
            const int lane = t & 63, w = t >> 6;
            const int ct = w & 1, kh = w >> 1;
            const int rb = u * 16;
            const int m = lane & 15, q = lane >> 4;
            const int row = rb + m;
            short8 a[4];
#pragma unroll
            for (int j = 0; j < 4; j++) {
                if (row < M) {
                    int k0 = (kh * 4 + j) * 32 + q * 8;
                    ushort4 r01 = *(const ushort4*)(p.rst + (size_t)row * 256 + k0);
                    ushort4 r23 = *(const ushort4*)(p.rst + (size_t)row * 256 + k0 + 4);
                    ushort4 h01 = *(const ushort4*)(p.hh + (size_t)row * 256 + k0);
                    ushort4 h23 = *(const ushort4*)(p.hh + (size_t)row * 256 + k0 + 4);
                    u16 rv[8] = {r01.x, r01.y, r01.z, r01.w, r23.x, r23.y, r23.z, r23.w};
                    u16 hv[8] = {h01.x, h01.y, h01.z, h01.w, h23.x, h23.y, h23.z, h23.w};
                    short8 av;
#pragma unroll
                    for (int jj = 0; jj < 8; jj++) {
                        int c = k0 + jj;
                        float y = sc[c] * bf2f(rv[jj]) + sh[c];
                        y = (y > 0.f) ? y : expm1f(y);
                        av[jj] = (short)f2bf(bf2f(hv[jj]) + y);
                    }
                    a[j] = av;
                } else a[j] = (short8){0, 0, 0, 0, 0, 0, 0, 0};
            }
            const short8* B8 = (const short8*)p.Bfc2;
            f32x4 acc = {0.f, 0.f, 0.f, 0.f};
#pragma unroll
            for (int j = 0; j < 4; j++)
                acc = __builtin_amdgcn_mfma_f32_16x16x32_bf16(a[j], B8[(ct * 8 + kh * 4 + j) * 64 + lane], acc, 0, 0, 0);
            if (kh == 1) *(f32x4*)&red[ct * 256 + lane * 4] = acc;
            __syncthreads();
            if (kh == 0) {
                f32x4 pp = *(const f32x4*)&red[ct * 256 + lane * 4];
#pragma unroll
                for (int r = 0; r < 4; r++) {
                    int rl = q * 4 + r;
                    int ro = rb + rl;
                    float v = 0.f;
                    if (ro < M) {
                        v = acc[r] + pp[r];
                        p.feat2[(size_t)ro * 32 + ct * 16 + m] = v;
                    }
                    tl[rl * 32 + ct * 16 + m] = v;
                }
            }
            __syncthreads();
            if (t < 16) {
                int node = rb + t;
                if (node < M) {
                    float a_ = 0.f, b_ = 0.f;
#pragma unroll
                    for (int d = 0; d < 32; d++) {
                        float fv = tl[t * 32 + d];
                        a_ += fv * p.al2[d];
                        b_ += fv * p.ar2[d];
                    }
                    p.el2[node] = a_;
                    p.er2[node] = b_;
                }
            }
            __syncthreads();  // smem reuse safety
        }
    }
    gbar(p.cnt, p.gen, GRID, bi++);

    // ================= P7: agg2 =================
    {
        const int NU = (p.N + 7) >> 3;
        for (int u = bid; u < NU; u += GRID) {
            const int node = u * 8 + (t >> 5);
            const int d = t & 31;
            if (node < p.N) {
                int beg = p.offs[node], end = p.offs[node + 1];
                if (beg < 0) beg = 0;
                if (end > p.E) end = p.E;
                float ern = p.er2[node];
                float acc = 0.f, sw = 0.f;
#pragma unroll 2
                for (int j = beg; j < end; j++) {
                    int s = p.srcs[j];
                    if ((unsigned)s >= (unsigned)p.N) continue;
                    float wv = edgew(p.el2[s] + ern);
                    sw += wv;
                    acc += wv * p.feat2[(size_t)s * 32 + d];
                }
                p.rst2[(size_t)node * 32 + d] = acc / (sw + 1e-16f);
            }
        }
    }
    gbar(p.cnt, p.gen, GRID, bi++);

    // ================= P8: bn stats over rst2 (32 cols) =================
    {
        float* ss = (float*)smem;    // 256
        float* ss2 = ss + 256;       // 256
        const int NU = (p.N + 63) >> 6;
        for (int u = bid; u < NU; u += GRID) {
            int c = t & 31, rs = t >> 5;
            int rbeg = u * 64;
            int rend = rbeg + 64;
            if (rend > p.N) rend = p.N;
            float s = 0.f, s2 = 0.f;
            for (int r = rbeg + rs; r < rend; r += 8) {
                float x = p.rst2[(size_t)r * 32 + c];
                s += x;
                s2 += x * x;
            }
            ss[t] = s;
            ss2[t] = s2;
            __syncthreads();
            if (t < 32) {
                for (int j = 32; j < 256; j += 32) { s += ss[t + j]; s2 += ss2[t + j]; }
                atomicAdd(&p.stats2[c], s);
                atomicAdd(&p.stats2[32 + c], s2);
            }
            __syncthreads();
        }
    }
    gbar(p.cnt, p.gen, GRID, bi++);

    // ================= P9: final bn + elu -> out =================
    {
        const float invN = 1.f / p.N;
        const int total = p.N * 32;
        for (int i = gtid; i < total; i += GT) {
            int c = i & 31;
            float mu = p.stats2[c] * invN;
            float var = fmaxf(p.stats2[32 + c] * invN - mu * mu, 0.f);
            float y = p.g2[c] * (p.rst2[i] - mu) * rsqrtf(var + 1e-5f) + p.b2[c];
            y = (y > 0.f) ? y : expm1f(y);
            p.out[i] = y;
        }
    }
}

extern "C" void kernel_launch(void* const* d_in, const int* in_sizes, int n_in, void* d_out, int out_size, void* d_ws,
                              size_t ws_size, hipStream_t stream) {
    const int N = out_size / ODIM;
    const int E = in_sizes[2];

    MegaP P;
    P.in_h = (const float*)d_in[0];
    P.src = (const int*)d_in[2];
    P.dst = (const int*)d_in[3];
    P.W_emb = (const float*)d_in[4];  P.bemb = (const float*)d_in[5];
    P.fc1w = (const float*)d_in[18];  P.al1 = (const float*)d_in[19];
    P.ar1 = (const float*)d_in[20];
    P.g1 = (const float*)d_in[21];    P.b1 = (const float*)d_in[22];
    P.fc2w = (const float*)d_in[23];  P.al2 = (const float*)d_in[24];
    P.ar2 = (const float*)d_in[25];
    P.g2 = (const float*)d_in[26];    P.b2 = (const float*)d_in[27];
    P.out = (float*)d_out;

    // ---- ws layout (~26 MB) ----
    char* base = (char*)d_ws;
    size_t off = 0;
    auto alloc = [&](size_t bytes) { void* p = base + off; off += (bytes + 63) & ~63ull; return p; };
    const size_t ZBYTES = (size_t)N * 4 + 512 * 4 + 64 * 4 + 256;  // deg, stats, stats2, barrier state
    char* zb = (char*)alloc(ZBYTES);
    P.deg = (int*)zb;
    P.stats = (float*)(zb + (size_t)N * 4);
    P.stats2 = P.stats + 512;
    P.cnt = (int*)(P.stats2 + 64);
    P.gen = P.cnt + 16;  // separate cache line-ish
    P.offs = (int*)alloc((size_t)(N + 1) * 4);
    P.cursor = (int*)alloc((size_t)N * 4);
    P.srcs = (int*)alloc((size_t)E * 4);
    P.Ah = (u16*)alloc((size_t)N * 128 * 2);
    P.Bemb = (u16*)alloc((size_t)128 * 256 * 2);
    P.Bfc1 = (u16*)alloc((size_t)256 * 256 * 2);
    P.Bfc2 = (u16*)alloc((size_t)256 * 32 * 2);
    P.hh = (u16*)alloc((size_t)N * HDIM * 2);
    P.feat1 = (u16*)alloc((size_t)N * HDIM * 2);
    P.el1 = (u16*)alloc((size_t)N * 8 * 2);
    P.er1 = (u16*)alloc((size_t)N * 8 * 2);
    P.rst = (u16*)alloc((size_t)N * HDIM * 2);
    P.feat2 = (float*)alloc((size_t)N * 32 * 4);
    P.el2 = (float*)alloc((size_t)N * 4);
    P.er2 = (float*)alloc((size_t)N * 4);
    P.rst2 = (float*)alloc((size_t)N * 32 * 4);

    P.N = N;
    P.E = E;
    P.n4 = N * 32;            // N*128/4 float4 groups
    P.NB16 = (N + 15) / 16;   // GEMM tile units
    P.NBF = (E + 255) / 256;  // fill units

    // occupancy-clamped grid: all blocks MUST be co-resident for gbar. Query once.
    static int g_grid = 0;
    if (g_grid == 0) {
        int nb = 0;
        hipError_t e =
            hipOccupancyMaxActiveBlocksPerMultiprocessor(&nb, reinterpret_cast<const void*>(mega), 256, 0);
        if (e != hipSuccess || nb < 1) nb = 1;  // 1 block/CU is always co-resident (8KB LDS, <=128 VGPR)
        if (nb > 4) nb = 4;
        g_grid = nb * 256;  // gfx950: 256 CUs
    }

    hipMemsetAsync(zb, 0, ZBYTES, stream);
    mega<<<dim3(g_grid), dim3(256), 0, stream>>>(P);
}